// Round 16
// baseline (233.051 us; speedup 1.0000x reference)
//
#include <hip/hip_runtime.h>

static inline int ceil_div(int a, int b) { return (a + b - 1) / b; }

typedef __attribute__((ext_vector_type(8))) short short8;   // 8 bf16 = 4 VGPR
typedef __attribute__((ext_vector_type(4))) float f32x4;

__device__ __forceinline__ ushort bf16_rne(float v) {
  uint u = __float_as_uint(v);
  return (ushort)((u + 0x7FFFu + ((u >> 16) & 1u)) >> 16);
}

// -------- weight pack (device): fp32 W -> RNE bf16, LDS-slot order -----------
// slot = (kt*4 + g)*NCOL + col ; element j of slot holds k = kt*32+g*8+j.
// This makes the gemm's LDS B-read consecutive-16B across lanes (conflict-free).
__device__ __forceinline__ void pack_dev(const float* __restrict__ Wl,
                                         const float* __restrict__ Wr,
                                         ushort* __restrict__ hi, int ct, int FOUT) {
  const int NCOL = 2 * FOUT;
  const int col = ct % NCOL;
  const int kg = ct / NCOL;
  const int g = kg & 3;
  const int kt = kg >> 2;
  uint hw[4];
#pragma unroll
  for (int w = 0; w < 4; ++w) {
    uint h2[2];
#pragma unroll
    for (int t = 0; t < 2; ++t) {
      int j = 2 * w + t;
      int k = kt * 32 + g * 8 + j;
      float v = (col < FOUT) ? Wl[k * FOUT + col] : Wr[k * FOUT + (col - FOUT)];
      h2[t] = (uint)bf16_rne(v);
    }
    hw[w] = h2[0] | (h2[1] << 16);
  }
  ((uint4*)hi)[ct] = make_uint4(hw[0], hw[1], hw[2], hw[3]);
}

// ==== prep mega-kernel: [0,16) pack0 | [16,32) pack1 | [32,40) pack2 |
//      [40,40+zb) zero cnt+flags | rest: x fp32->bf16 convert ================
__global__ void k_prep(const float* __restrict__ Wl0, const float* __restrict__ Wr0,
                       ushort* __restrict__ hi0,
                       const float* __restrict__ Wl1, const float* __restrict__ Wr1,
                       ushort* __restrict__ hi1,
                       const float* __restrict__ Wl2, const float* __restrict__ Wr2,
                       ushort* __restrict__ hi2,
                       const float* __restrict__ x, ushort* __restrict__ xb,
                       int* __restrict__ cnt, int* __restrict__ bflag,
                       int n, int zb) {
  const int b = blockIdx.x;
  const int tid = threadIdx.x;
  if (b < 16) {
    pack_dev(Wl0, Wr0, hi0, b * 256 + tid, 128);
  } else if (b < 32) {
    pack_dev(Wl1, Wr1, hi1, (b - 16) * 256 + tid, 128);
  } else if (b < 40) {
    pack_dev(Wl2, Wr2, hi2, (b - 32) * 256 + tid, 64);
  } else if (b < 40 + zb) {
    int b2 = b - 40;
    int i0 = b2 * 2048 + tid;
#pragma unroll
    for (int j = 0; j < 8; ++j) {
      int i = i0 + j * 256;
      if (i < n) cnt[i] = 0;
    }
    if (b2 == 0 && tid < 32) bflag[tid] = 0;
  } else {
    int i = (b - 40 - zb) * 256 + tid;
    if (i < n * 16) {
      const float4* ip = (const float4*)(x + (size_t)i * 8);
      float4 a = ip[0], bb = ip[1];
      uint p0 = (uint)bf16_rne(a.x) | ((uint)bf16_rne(a.y) << 16);
      uint p1 = (uint)bf16_rne(a.z) | ((uint)bf16_rne(a.w) << 16);
      uint p2 = (uint)bf16_rne(bb.x) | ((uint)bf16_rne(bb.y) << 16);
      uint p3 = (uint)bf16_rne(bb.z) | ((uint)bf16_rne(bb.w) << 16);
      ((uint4*)xb)[i] = make_uint4(p0, p1, p2, p3);
    }
  }
}

// ---------------- CSR build ----------------

// histogram + per-edge rank (ushort ranks; 4 atomics in flight)
__global__ void k_count_rank(const int* __restrict__ dst, int* __restrict__ cnt,
                             ushort* __restrict__ rank, int e) {
  int i0 = (blockIdx.x * blockDim.x + threadIdx.x) * 4;
  if (i0 >= e) return;
  int d[4], r[4];
  if (i0 + 3 < e) {
    int4 dv = *(const int4*)(dst + i0);
    d[0] = dv.x; d[1] = dv.y; d[2] = dv.z; d[3] = dv.w;
  } else {
#pragma unroll
    for (int j = 0; j < 4; ++j) d[j] = (i0 + j < e) ? dst[i0 + j] : 0;
  }
#pragma unroll
  for (int j = 0; j < 4; ++j)
    if (i0 + j < e) r[j] = atomicAdd(&cnt[d[j]], 1);
  if (i0 + 3 < e) {
    ushort4 rv;
    rv.x = (ushort)r[0]; rv.y = (ushort)r[1];
    rv.z = (ushort)r[2]; rv.w = (ushort)r[3];
    *(ushort4*)(rank + i0) = rv;
  } else {
#pragma unroll
    for (int j = 0; j < 4; ++j)
      if (i0 + j < e) rank[i0 + j] = (ushort)r[j];
  }
}

// ---- single-kernel scan, decoupled lookback: row_ptr (exclusive) + inv ------
#define SCAN_BS 256
#define SCAN_VPT 8
#define SCAN_CHUNK (SCAN_BS * SCAN_VPT)

__global__ __launch_bounds__(SCAN_BS) void k_scan_lb(const int* __restrict__ cnt,
                                                     int* __restrict__ row_ptr,
                                                     float* __restrict__ inv,
                                                     int* __restrict__ bflag,
                                                     int n, int nblocks) {
  __shared__ int s[SCAN_BS];
  __shared__ int s_prev;
  const int tid = threadIdx.x;
  const int bid = blockIdx.x;
  const int i0 = bid * SCAN_CHUNK + tid * SCAN_VPT;
  int v[SCAN_VPT], cv[SCAN_VPT];
  int sum = 0;
#pragma unroll
  for (int j = 0; j < SCAN_VPT; ++j) {
    int i = i0 + j;
    int c = (i < n) ? cnt[i] : 0;
    cv[j] = c;
    v[j] = sum;
    sum += c;
  }
  s[tid] = sum;
  __syncthreads();
  for (int off = 1; off < SCAN_BS; off <<= 1) {
    int t = (tid >= off) ? s[tid - off] : 0;
    __syncthreads();
    s[tid] += t;
    __syncthreads();
  }
  const int btotal = s[SCAN_BS - 1];
  if (tid == 0) {
    atomicExch(&bflag[bid], btotal + 1);  // publish (value carries the sum)
    int prev = 0;
    for (int b = 0; b < bid; ++b) {
      int f;
      do { f = atomicAdd(&bflag[b], 0); } while (f == 0);
      prev += f - 1;
    }
    s_prev = prev;
    if (bid == nblocks - 1) row_ptr[n] = prev + btotal;
  }
  __syncthreads();
  const int excl = s_prev + s[tid] - sum;
#pragma unroll
  for (int j = 0; j < SCAN_VPT; ++j) {
    int i = i0 + j;
    if (i < n) {
      row_ptr[i] = excl + v[j];
      inv[i] = 1.0f / (float)(cv[j] > 1 ? cv[j] : 1);
    }
  }
}

// place edges: csr16[row_ptr[dst] + rank] = (ushort)src ; no atomics
__global__ void k_place(const int* __restrict__ src, const int* __restrict__ dst,
                        const ushort* __restrict__ rank, const int* __restrict__ row_ptr,
                        ushort* __restrict__ csr16, int e) {
  int i0 = (blockIdx.x * blockDim.x + threadIdx.x) * 4;
  if (i0 >= e) return;
  if (i0 + 3 < e) {
    int4 dv = *(const int4*)(dst + i0);
    int4 sv = *(const int4*)(src + i0);
    ushort4 rv = *(const ushort4*)(rank + i0);
    int p0 = row_ptr[dv.x], p1 = row_ptr[dv.y], p2 = row_ptr[dv.z], p3 = row_ptr[dv.w];
    csr16[p0 + rv.x] = (ushort)sv.x;
    csr16[p1 + rv.y] = (ushort)sv.y;
    csr16[p2 + rv.z] = (ushort)sv.z;
    csr16[p3 + rv.w] = (ushort)sv.w;
  } else {
#pragma unroll
    for (int j = 0; j < 4; ++j) {
      int i = i0 + j;
      if (i < e) csr16[row_ptr[dst[i]] + rank[i]] = (ushort)src[i];
    }
  }
}

// ==== persistent-weight dual GEMM: W resident in LDS, blocks iterate tiles ===
// Zb(bf16) = A@Wl ; Rb(bf16) = A@Wr + b. Per block: load full W into LDS once,
// then loop row-tiles (32 rows each) with issue-early/write-late A staging.
template <int FOUT>
__global__ __launch_bounds__(256) void k_gemm2p(const ushort* __restrict__ Hb,
                                                const ushort* __restrict__ Whi,
                                                const float* __restrict__ bias,
                                                ushort* __restrict__ Zb,
                                                ushort* __restrict__ Rb, int n) {
  constexpr int NCOL = 2 * FOUT;
  constexpr int NT = NCOL / 64;
  constexpr int MT = 2;
  constexpr int WCH = NCOL * 16;      // uint4 slots of weight (4096 / 2048)
  __shared__ uint4 sW[WCH];           // 64KB / 32KB
  __shared__ uint4 sA[32 * 16];       // 8KB

  const int tid = threadIdx.x;
  const int lane = tid & 63;
  const int wave = tid >> 6;
  const int n0 = wave * (NCOL / 4);
  const int g16 = lane >> 4;
  const int l16 = lane & 15;
  const int TILES = (n + 31) >> 5;
  const int GRIDN = gridDim.x;

  // ---- load full weights into LDS (once) ----
  const uint4* Wg = (const uint4*)Whi;
#pragma unroll
  for (int i = tid; i < WCH; i += 256) sW[i] = Wg[i];

  // ---- stage first tile ----
  {
    int tile = blockIdx.x;
    if (tile < TILES) {
      int row0 = tile * 32;
#pragma unroll
      for (int c = tid; c < 512; c += 256) {
        int srow = c >> 4, col16 = c & 15;
        int g = row0 + srow;
        uint4 v = make_uint4(0u, 0u, 0u, 0u);
        if (g < n) v = *(const uint4*)(Hb + (size_t)g * 128 + col16 * 8);
        sA[srow * 16 + (col16 ^ (srow & 7))] = v;
      }
    }
  }
  __syncthreads();

  const float badd0 = bias[(n0 + l16) % FOUT];  // placeholder; per-nt below

  for (int tile = blockIdx.x; tile < TILES; tile += GRIDN) {
    const int row0 = tile * 32;
    const int ntile = tile + GRIDN;
    const bool havenext = ntile < TILES;

    // ---- issue next tile's A loads early (hide under MFMAs) ----
    uint4 rr[2];
    if (havenext) {
      int nrow0 = ntile * 32;
#pragma unroll
      for (int k = 0; k < 2; ++k) {
        int c = tid + k * 256;
        int g = nrow0 + (c >> 4);
        rr[k] = make_uint4(0u, 0u, 0u, 0u);
        if (g < n) rr[k] = *(const uint4*)(Hb + (size_t)g * 128 + (c & 15) * 8);
      }
    }

    // ---- compute: pure LDS + MFMA ----
    f32x4 acc[MT][NT];
#pragma unroll
    for (int mt = 0; mt < MT; ++mt)
#pragma unroll
      for (int nt = 0; nt < NT; ++nt) acc[mt][nt] = (f32x4)(0.f);

#pragma unroll
    for (int kt = 0; kt < 4; ++kt) {
      short8 a[MT];
#pragma unroll
      for (int mt = 0; mt < MT; ++mt) {
        int row = mt * 16 + l16;
        int slot = (kt * 4 + g16) ^ (row & 7);
        a[mt] = *(const short8*)&sA[row * 16 + slot];
      }
#pragma unroll
      for (int nt = 0; nt < NT; ++nt) {
        short8 b = *(const short8*)&sW[(kt * 4 + g16) * NCOL + n0 + nt * 16 + l16];
#pragma unroll
        for (int mt = 0; mt < MT; ++mt)
          acc[mt][nt] = __builtin_amdgcn_mfma_f32_16x16x32_bf16(a[mt], b, acc[mt][nt], 0, 0, 0);
      }
    }

    __syncthreads();  // all waves done reading sA

    // ---- write-late: next tile into sA ----
    if (havenext) {
#pragma unroll
      for (int k = 0; k < 2; ++k) {
        int c = tid + k * 256;
        sA[(c >> 4) * 16 + ((c & 15) ^ ((c >> 4) & 7))] = rr[k];
      }
    }

    // ---- epilogue (global stores overlap the ds_writes) ----
#pragma unroll
    for (int nt = 0; nt < NT; ++nt) {
      int col = n0 + nt * 16 + l16;
      bool isR = col >= FOUT;
      int cw = isR ? col - FOUT : col;
      float badd = isR ? bias[cw] : 0.f;
      ushort* base = isR ? Rb : Zb;
#pragma unroll
      for (int mt = 0; mt < MT; ++mt) {
#pragma unroll
        for (int j = 0; j < 4; ++j) {
          int row = row0 + mt * 16 + g16 * 4 + j;
          if (row < n) base[(size_t)row * FOUT + cw] = bf16_rne(acc[mt][nt][j] + badd);
        }
      }
    }

    __syncthreads();  // sA ready for next iteration
  }
  (void)badd0;
}

// -------- CSR mean-aggregation + epilogue: out = act(mean(Zb)*inv + Rb) ------
template <int FOUT, bool RELU, bool OUTB>
__global__ __launch_bounds__(256) void k_agg2(const ushort* __restrict__ Zb,
                                              const ushort* __restrict__ Rb,
                                              const int* __restrict__ row_ptr,
                                              const ushort* __restrict__ csr16,
                                              const float* __restrict__ inv,
                                              void* __restrict__ outp, int n) {
  constexpr int FL = FOUT / 8;            // lanes per row (16 or 8)
  constexpr int EG = 64 / FL;             // edge groups per wave (4 or 8)
  constexpr int DEPTH = (FL == 16) ? 8 : 4;
  const int lane = threadIdx.x & 63;
  const int node = blockIdx.x * 4 + (threadIdx.x >> 6);
  if (node >= n) return;
  const int c = lane % FL;
  const int eg = lane / FL;

  const int e0 = row_ptr[node];
  const int m = row_ptr[node + 1] - e0;  // wave-uniform
  const uint4* Z4 = (const uint4*)Zb;    // 16B = 8 bf16

  // hoist R load: latency hides under the gather loop
  uint4 rw = make_uint4(0u, 0u, 0u, 0u);
  if (eg == 0) rw = ((const uint4*)Rb)[(size_t)node * FL + c];

  float acc[8];
#pragma unroll
  for (int k = 0; k < 8; ++k) acc[k] = 0.f;

  int t = eg;
  while (t < m) {
    int ss[DEPTH];
#pragma unroll
    for (int j = 0; j < DEPTH; ++j) {
      int tj = t + j * EG;
      int tc = (tj < m) ? tj : (m - 1);  // clamped: always valid
      ss[j] = csr16[e0 + tc];
    }
    uint4 z[DEPTH];
#pragma unroll
    for (int j = 0; j < DEPTH; ++j) z[j] = Z4[(size_t)ss[j] * FL + c];
#pragma unroll
    for (int j = 0; j < DEPTH; ++j) {
      if (t + j * EG < m) {
        const uint* zw = (const uint*)&z[j];
#pragma unroll
        for (int w = 0; w < 4; ++w) {
          acc[2 * w]     += __uint_as_float(zw[w] << 16);
          acc[2 * w + 1] += __uint_as_float(zw[w] & 0xFFFF0000u);
        }
      }
    }
    t += DEPTH * EG;
  }

#pragma unroll
  for (int off = FL; off < 64; off <<= 1) {
#pragma unroll
    for (int k = 0; k < 8; ++k) acc[k] += __shfl_xor(acc[k], off, 64);
  }

  if (eg == 0) {
    const float iv = inv[node];
    const uint* rp = (const uint*)&rw;
    float o[8];
#pragma unroll
    for (int w = 0; w < 4; ++w) {
      o[2 * w]     = fmaf(acc[2 * w],     iv, __uint_as_float(rp[w] << 16));
      o[2 * w + 1] = fmaf(acc[2 * w + 1], iv, __uint_as_float(rp[w] & 0xFFFF0000u));
    }
    if (RELU) {
#pragma unroll
      for (int k = 0; k < 8; ++k) o[k] = fmaxf(o[k], 0.f);
    }
    if (OUTB) {
      uint p[4];
#pragma unroll
      for (int w = 0; w < 4; ++w)
        p[w] = (uint)bf16_rne(o[2 * w]) | ((uint)bf16_rne(o[2 * w + 1]) << 16);
      ((uint4*)outp)[(size_t)node * FL + c] = make_uint4(p[0], p[1], p[2], p[3]);
    } else {
      float4* op = (float4*)((float*)outp + (size_t)node * FOUT + c * 8);
      op[0] = make_float4(o[0], o[1], o[2], o[3]);
      op[1] = make_float4(o[4], o[5], o[6], o[7]);
    }
  }
}

// ---------------- launch ----------------

extern "C" void kernel_launch(void* const* d_in, const int* in_sizes, int n_in,
                              void* d_out, int out_size, void* d_ws, size_t ws_size,
                              hipStream_t stream) {
  const float* x   = (const float*)d_in[0];
  const int*   ei  = (const int*)d_in[1];
  const float* Wl0 = (const float*)d_in[2];
  const float* bl0 = (const float*)d_in[3];
  const float* Wr0 = (const float*)d_in[4];
  const float* Wl1 = (const float*)d_in[5];
  const float* bl1 = (const float*)d_in[6];
  const float* Wr1 = (const float*)d_in[7];
  const float* Wl2 = (const float*)d_in[8];
  const float* bl2 = (const float*)d_in[9];
  const float* Wr2 = (const float*)d_in[10];
  float* out = (float*)d_out;

  const int N = in_sizes[0] / 128;
  const int E = in_sizes[1] / 2;
  const int* src = ei;
  const int* dst = ei + E;

  char* w = (char*)d_ws;
  auto alloc = [&](size_t bytes) {
    char* p = w;
    w += (bytes + 255) & ~(size_t)255;
    return p;
  };
  int*    cnt     = (int*)alloc((size_t)N * 4);
  int*    row_ptr = (int*)alloc((size_t)(N + 1) * 4);
  int*    bflag   = (int*)alloc(32 * 4);
  ushort* rank    = (ushort*)alloc((size_t)E * 2 + 256);
  ushort* csr16   = (ushort*)alloc((size_t)E * 2 + 256);
  float*  inv     = (float*)alloc((size_t)N * 4);
  ushort* Whi0    = (ushort*)alloc((size_t)4 * 256 * 4 * 16);
  ushort* Whi1    = (ushort*)alloc((size_t)4 * 256 * 4 * 16);
  ushort* Whi2    = (ushort*)alloc((size_t)4 * 128 * 4 * 16);
  ushort* XB      = (ushort*)alloc((size_t)N * 128 * 2);  // x in bf16
  ushort* BZ      = (ushort*)alloc((size_t)N * 128 * 2);
  ushort* BRb     = (ushort*)alloc((size_t)N * 128 * 2);  // R in bf16
  ushort* B0      = (ushort*)alloc((size_t)N * 128 * 2);  // H in bf16
  (void)ws_size; (void)n_in; (void)out_size;

  const int ZB = ceil_div(N, 2048);             // zero-range blocks
  const int PS = ceil_div(N, SCAN_CHUNK);       // scan blocks (25 <= 32)
  const int PREP_B = 40 + ZB + ceil_div(N * 16, 256);
  const int TILES = ceil_div(N, 32);
  const int G128 = (TILES < 512) ? TILES : 512;    // 2 blocks/CU @72KB LDS
  const int G64  = (TILES < 1024) ? TILES : 1024;  // 4 blocks/CU @40KB LDS

  // ---- prep: packs + cvt + zero (1 launch) ----
  k_prep<<<PREP_B, 256, 0, stream>>>(Wl0, Wr0, Whi0, Wl1, Wr1, Whi1,
                                     Wl2, Wr2, Whi2, x, XB, cnt, bflag, N, ZB);

  // ---- CSR build: count_rank -> lookback scan -> place (3 launches) ----
  k_count_rank<<<ceil_div(E, 1024), 256, 0, stream>>>(dst, cnt, rank, E);
  k_scan_lb<<<PS, SCAN_BS, 0, stream>>>(cnt, row_ptr, inv, bflag, N, PS);
  k_place<<<ceil_div(E, 1024), 256, 0, stream>>>(src, dst, rank, row_ptr, csr16, E);

  // ---- layer 0: xb -> (Zb,Rb) -> H1 bf16 (B0) ----
  k_gemm2p<128><<<G128, 256, 0, stream>>>(XB, Whi0, bl0, BZ, BRb, N);
  k_agg2<128, true, true><<<ceil_div(N, 4), 256, 0, stream>>>(BZ, BRb, row_ptr, csr16, inv, B0, N);

  // ---- layer 1: H1 bf16 -> (Zb,Rb) -> H2 bf16 (B0) ----
  k_gemm2p<128><<<G128, 256, 0, stream>>>(B0, Whi1, bl1, BZ, BRb, N);
  k_agg2<128, true, true><<<ceil_div(N, 4), 256, 0, stream>>>(BZ, BRb, row_ptr, csr16, inv, B0, N);

  // ---- layer 2: H2 bf16 -> (Zb,Rb) 64-wide -> out fp32 ----
  k_gemm2p<64><<<G64, 256, 0, stream>>>(B0, Whi2, bl2, BZ, BRb, N);
  k_agg2<64, false, false><<<ceil_div(N, 4), 256, 0, stream>>>(BZ, BRb, row_ptr, csr16, inv, out, N);
}

// Round 17
// 217.818 us; speedup vs baseline: 1.0699x; 1.0699x over previous
//
#include <hip/hip_runtime.h>

static inline int ceil_div(int a, int b) { return (a + b - 1) / b; }

typedef __attribute__((ext_vector_type(8))) short short8;   // 8 bf16 = 4 VGPR
typedef __attribute__((ext_vector_type(4))) float f32x4;

__device__ __forceinline__ ushort bf16_rne(float v) {
  uint u = __float_as_uint(v);
  return (ushort)((u + 0x7FFFu + ((u >> 16) & 1u)) >> 16);
}

// -------- weight pack (device): fp32 W -> RNE bf16, MFMA-B-fragment order ----
// chunk ct = (kt*NCOL + col)*4 + g ; element j holds k = kt*32+g*8+j.
__device__ __forceinline__ void pack_dev(const float* __restrict__ Wl,
                                         const float* __restrict__ Wr,
                                         ushort* __restrict__ hi, int ct, int FOUT) {
  const int NCOL = 2 * FOUT;
  const int g = ct & 3;
  const int nn = (ct >> 2) % NCOL;
  const int kt = ct / (4 * NCOL);
  uint hw[4];
#pragma unroll
  for (int w = 0; w < 4; ++w) {
    uint h2[2];
#pragma unroll
    for (int t = 0; t < 2; ++t) {
      int j = 2 * w + t;
      int k = kt * 32 + g * 8 + j;
      float v = (nn < FOUT) ? Wl[k * FOUT + nn] : Wr[k * FOUT + (nn - FOUT)];
      h2[t] = (uint)bf16_rne(v);
    }
    hw[w] = h2[0] | (h2[1] << 16);
  }
  ((uint4*)hi)[ct] = make_uint4(hw[0], hw[1], hw[2], hw[3]);
}

// ==== prep mega-kernel: [0,16) pack0 | [16,32) pack1 | [32,40) pack2 |
//      [40,40+zb) zero cnt+flags | rest: x fp32->bf16 convert ================
__global__ void k_prep(const float* __restrict__ Wl0, const float* __restrict__ Wr0,
                       ushort* __restrict__ hi0,
                       const float* __restrict__ Wl1, const float* __restrict__ Wr1,
                       ushort* __restrict__ hi1,
                       const float* __restrict__ Wl2, const float* __restrict__ Wr2,
                       ushort* __restrict__ hi2,
                       const float* __restrict__ x, ushort* __restrict__ xb,
                       int* __restrict__ cnt, int* __restrict__ bflag,
                       int n, int zb) {
  const int b = blockIdx.x;
  const int tid = threadIdx.x;
  if (b < 16) {
    pack_dev(Wl0, Wr0, hi0, b * 256 + tid, 128);
  } else if (b < 32) {
    pack_dev(Wl1, Wr1, hi1, (b - 16) * 256 + tid, 128);
  } else if (b < 40) {
    pack_dev(Wl2, Wr2, hi2, (b - 32) * 256 + tid, 64);
  } else if (b < 40 + zb) {
    int b2 = b - 40;
    int i0 = b2 * 2048 + tid;
#pragma unroll
    for (int j = 0; j < 8; ++j) {
      int i = i0 + j * 256;
      if (i < n) cnt[i] = 0;
    }
    if (b2 == 0 && tid < 32) bflag[tid] = 0;
  } else {
    int i = (b - 40 - zb) * 256 + tid;
    if (i < n * 16) {
      const float4* ip = (const float4*)(x + (size_t)i * 8);
      float4 a = ip[0], bb = ip[1];
      uint p0 = (uint)bf16_rne(a.x) | ((uint)bf16_rne(a.y) << 16);
      uint p1 = (uint)bf16_rne(a.z) | ((uint)bf16_rne(a.w) << 16);
      uint p2 = (uint)bf16_rne(bb.x) | ((uint)bf16_rne(bb.y) << 16);
      uint p3 = (uint)bf16_rne(bb.z) | ((uint)bf16_rne(bb.w) << 16);
      ((uint4*)xb)[i] = make_uint4(p0, p1, p2, p3);
    }
  }
}

// ---------------- CSR build ----------------

// histogram + per-edge rank (ushort ranks; 4 atomics in flight)
__global__ void k_count_rank(const int* __restrict__ dst, int* __restrict__ cnt,
                             ushort* __restrict__ rank, int e) {
  int i0 = (blockIdx.x * blockDim.x + threadIdx.x) * 4;
  if (i0 >= e) return;
  int d[4], r[4];
  if (i0 + 3 < e) {
    int4 dv = *(const int4*)(dst + i0);
    d[0] = dv.x; d[1] = dv.y; d[2] = dv.z; d[3] = dv.w;
  } else {
#pragma unroll
    for (int j = 0; j < 4; ++j) d[j] = (i0 + j < e) ? dst[i0 + j] : 0;
  }
#pragma unroll
  for (int j = 0; j < 4; ++j)
    if (i0 + j < e) r[j] = atomicAdd(&cnt[d[j]], 1);
  if (i0 + 3 < e) {
    ushort4 rv;
    rv.x = (ushort)r[0]; rv.y = (ushort)r[1];
    rv.z = (ushort)r[2]; rv.w = (ushort)r[3];
    *(ushort4*)(rank + i0) = rv;
  } else {
#pragma unroll
    for (int j = 0; j < 4; ++j)
      if (i0 + j < e) rank[i0 + j] = (ushort)r[j];
  }
}

// ---- single-kernel scan, decoupled lookback: row_ptr (exclusive) + inv ------
#define SCAN_BS 256
#define SCAN_VPT 8
#define SCAN_CHUNK (SCAN_BS * SCAN_VPT)

__global__ __launch_bounds__(SCAN_BS) void k_scan_lb(const int* __restrict__ cnt,
                                                     int* __restrict__ row_ptr,
                                                     float* __restrict__ inv,
                                                     int* __restrict__ bflag,
                                                     int n, int nblocks) {
  __shared__ int s[SCAN_BS];
  __shared__ int s_prev;
  const int tid = threadIdx.x;
  const int bid = blockIdx.x;
  const int i0 = bid * SCAN_CHUNK + tid * SCAN_VPT;
  int v[SCAN_VPT], cv[SCAN_VPT];
  int sum = 0;
#pragma unroll
  for (int j = 0; j < SCAN_VPT; ++j) {
    int i = i0 + j;
    int c = (i < n) ? cnt[i] : 0;
    cv[j] = c;
    v[j] = sum;
    sum += c;
  }
  s[tid] = sum;
  __syncthreads();
  for (int off = 1; off < SCAN_BS; off <<= 1) {
    int t = (tid >= off) ? s[tid - off] : 0;
    __syncthreads();
    s[tid] += t;
    __syncthreads();
  }
  const int btotal = s[SCAN_BS - 1];
  if (tid == 0) {
    atomicExch(&bflag[bid], btotal + 1);  // publish (value carries the sum)
    int prev = 0;
    for (int b = 0; b < bid; ++b) {
      int f;
      do { f = atomicAdd(&bflag[b], 0); } while (f == 0);
      prev += f - 1;
    }
    s_prev = prev;
    if (bid == nblocks - 1) row_ptr[n] = prev + btotal;
  }
  __syncthreads();
  const int excl = s_prev + s[tid] - sum;
#pragma unroll
  for (int j = 0; j < SCAN_VPT; ++j) {
    int i = i0 + j;
    if (i < n) {
      row_ptr[i] = excl + v[j];
      inv[i] = 1.0f / (float)(cv[j] > 1 ? cv[j] : 1);
    }
  }
}

// place edges: csr16[row_ptr[dst] + rank] = (ushort)src ; no atomics
__global__ void k_place(const int* __restrict__ src, const int* __restrict__ dst,
                        const ushort* __restrict__ rank, const int* __restrict__ row_ptr,
                        ushort* __restrict__ csr16, int e) {
  int i0 = (blockIdx.x * blockDim.x + threadIdx.x) * 4;
  if (i0 >= e) return;
  if (i0 + 3 < e) {
    int4 dv = *(const int4*)(dst + i0);
    int4 sv = *(const int4*)(src + i0);
    ushort4 rv = *(const ushort4*)(rank + i0);
    int p0 = row_ptr[dv.x], p1 = row_ptr[dv.y], p2 = row_ptr[dv.z], p3 = row_ptr[dv.w];
    csr16[p0 + rv.x] = (ushort)sv.x;
    csr16[p1 + rv.y] = (ushort)sv.y;
    csr16[p2 + rv.z] = (ushort)sv.z;
    csr16[p3 + rv.w] = (ushort)sv.w;
  } else {
#pragma unroll
    for (int j = 0; j < 4; ++j) {
      int i = i0 + j;
      if (i < e) csr16[row_ptr[dst[i]] + rank[i]] = (ushort)src[i];
    }
  }
}

// -------- all layers: A bf16 x W bf16, LDS-staged, weight-prefetch pipeline --
// (R16 lesson: persistent-weight variant regressed -- 2 blocks/CU starved TLP;
//  this 1563-block 32-row shape is the proven optimum for these small GEMMs.)
template <int FOUT>
__global__ __launch_bounds__(256) void k_gemm2b(const ushort* __restrict__ Hb,
                                                const ushort* __restrict__ Whi,
                                                const float* __restrict__ bias,
                                                ushort* __restrict__ Zb,
                                                ushort* __restrict__ Rb, int n) {
  constexpr int NCOL = 2 * FOUT;
  constexpr int NT = NCOL / 64;
  constexpr int MT = 2;
  __shared__ uint4 sA[32 * 16];  // 8KB: 32 rows x 16 slots of 16B

  const int tid = threadIdx.x;
  const int lane = tid & 63;
  const int wave = tid >> 6;
  const int row0 = blockIdx.x * 32;

  const int n0 = wave * (NCOL / 4);
  const int g16 = lane >> 4;
  const int l16 = lane & 15;

#pragma unroll
  for (int c = tid; c < 512; c += 256) {
    int srow = c >> 4, col16 = c & 15;
    int g = row0 + srow;
    uint4 v = make_uint4(0u, 0u, 0u, 0u);
    if (g < n) v = *(const uint4*)(Hb + (size_t)g * 128 + col16 * 8);
    sA[srow * 16 + (col16 ^ (srow & 7))] = v;
  }

  // prefetch kt=0 weights (independent of LDS; issued before the barrier)
  short8 bh[NT], bhN[NT];
#pragma unroll
  for (int nt = 0; nt < NT; ++nt) {
    size_t chunk = (size_t)(0 * NCOL + n0 + nt * 16 + l16) * 4 + g16;
    bh[nt] = *(const short8*)(Whi + chunk * 8);
  }
  __syncthreads();

  f32x4 acc[MT][NT];
#pragma unroll
  for (int mt = 0; mt < MT; ++mt)
#pragma unroll
    for (int nt = 0; nt < NT; ++nt) acc[mt][nt] = (f32x4)(0.f);

#pragma unroll
  for (int kt = 0; kt < 4; ++kt) {
    short8 a[MT];
#pragma unroll
    for (int mt = 0; mt < MT; ++mt) {
      int row = mt * 16 + l16;
      int slot = (kt * 4 + g16) ^ (row & 7);
      a[mt] = *(const short8*)&sA[row * 16 + slot];
    }
    if (kt < 3) {
#pragma unroll
      for (int nt = 0; nt < NT; ++nt) {
        size_t chunk = (size_t)((kt + 1) * NCOL + n0 + nt * 16 + l16) * 4 + g16;
        bhN[nt] = *(const short8*)(Whi + chunk * 8);
      }
    }
#pragma unroll
    for (int mt = 0; mt < MT; ++mt)
#pragma unroll
      for (int nt = 0; nt < NT; ++nt)
        acc[mt][nt] = __builtin_amdgcn_mfma_f32_16x16x32_bf16(a[mt], bh[nt], acc[mt][nt], 0, 0, 0);
    if (kt < 3) {
#pragma unroll
      for (int nt = 0; nt < NT; ++nt) bh[nt] = bhN[nt];
    }
  }

#pragma unroll
  for (int nt = 0; nt < NT; ++nt) {
    int col = n0 + nt * 16 + l16;
    bool isR = col >= FOUT;
    int cw = isR ? col - FOUT : col;
    float badd = isR ? bias[cw] : 0.f;
    ushort* base = isR ? Rb : Zb;
#pragma unroll
    for (int mt = 0; mt < MT; ++mt) {
#pragma unroll
      for (int j = 0; j < 4; ++j) {
        int row = row0 + mt * 16 + g16 * 4 + j;
        if (row < n) base[(size_t)row * FOUT + cw] = bf16_rne(acc[mt][nt][j] + badd);
      }
    }
  }
}

// -------- CSR mean-aggregation + epilogue: out = act(mean(Zb)*inv + Rb) ------
// Rb load hoisted above the gather loop (latency hides under it).
template <int FOUT, bool RELU, bool OUTB>
__global__ __launch_bounds__(256) void k_agg2(const ushort* __restrict__ Zb,
                                              const ushort* __restrict__ Rb,
                                              const int* __restrict__ row_ptr,
                                              const ushort* __restrict__ csr16,
                                              const float* __restrict__ inv,
                                              void* __restrict__ outp, int n) {
  constexpr int FL = FOUT / 8;            // lanes per row (16 or 8)
  constexpr int EG = 64 / FL;             // edge groups per wave (4 or 8)
  constexpr int DEPTH = (FL == 16) ? 8 : 4;
  const int lane = threadIdx.x & 63;
  const int node = blockIdx.x * 4 + (threadIdx.x >> 6);
  if (node >= n) return;
  const int c = lane % FL;
  const int eg = lane / FL;

  const int e0 = row_ptr[node];
  const int m = row_ptr[node + 1] - e0;  // wave-uniform
  const uint4* Z4 = (const uint4*)Zb;    // 16B = 8 bf16

  uint4 rw = make_uint4(0u, 0u, 0u, 0u);
  if (eg == 0) rw = ((const uint4*)Rb)[(size_t)node * FL + c];

  float acc[8];
#pragma unroll
  for (int k = 0; k < 8; ++k) acc[k] = 0.f;

  int t = eg;
  while (t < m) {
    int ss[DEPTH];
#pragma unroll
    for (int j = 0; j < DEPTH; ++j) {
      int tj = t + j * EG;
      int tc = (tj < m) ? tj : (m - 1);  // clamped: always valid
      ss[j] = csr16[e0 + tc];
    }
    uint4 z[DEPTH];
#pragma unroll
    for (int j = 0; j < DEPTH; ++j) z[j] = Z4[(size_t)ss[j] * FL + c];
#pragma unroll
    for (int j = 0; j < DEPTH; ++j) {
      if (t + j * EG < m) {
        const uint* zw = (const uint*)&z[j];
#pragma unroll
        for (int w = 0; w < 4; ++w) {
          acc[2 * w]     += __uint_as_float(zw[w] << 16);
          acc[2 * w + 1] += __uint_as_float(zw[w] & 0xFFFF0000u);
        }
      }
    }
    t += DEPTH * EG;
  }

#pragma unroll
  for (int off = FL; off < 64; off <<= 1) {
#pragma unroll
    for (int k = 0; k < 8; ++k) acc[k] += __shfl_xor(acc[k], off, 64);
  }

  if (eg == 0) {
    const float iv = inv[node];
    const uint* rp = (const uint*)&rw;
    float o[8];
#pragma unroll
    for (int w = 0; w < 4; ++w) {
      o[2 * w]     = fmaf(acc[2 * w],     iv, __uint_as_float(rp[w] << 16));
      o[2 * w + 1] = fmaf(acc[2 * w + 1], iv, __uint_as_float(rp[w] & 0xFFFF0000u));
    }
    if (RELU) {
#pragma unroll
      for (int k = 0; k < 8; ++k) o[k] = fmaxf(o[k], 0.f);
    }
    if (OUTB) {
      uint p[4];
#pragma unroll
      for (int w = 0; w < 4; ++w)
        p[w] = (uint)bf16_rne(o[2 * w]) | ((uint)bf16_rne(o[2 * w + 1]) << 16);
      ((uint4*)outp)[(size_t)node * FL + c] = make_uint4(p[0], p[1], p[2], p[3]);
    } else {
      float4* op = (float4*)((float*)outp + (size_t)node * FOUT + c * 8);
      op[0] = make_float4(o[0], o[1], o[2], o[3]);
      op[1] = make_float4(o[4], o[5], o[6], o[7]);
    }
  }
}

// ---------------- launch ----------------

extern "C" void kernel_launch(void* const* d_in, const int* in_sizes, int n_in,
                              void* d_out, int out_size, void* d_ws, size_t ws_size,
                              hipStream_t stream) {
  const float* x   = (const float*)d_in[0];
  const int*   ei  = (const int*)d_in[1];
  const float* Wl0 = (const float*)d_in[2];
  const float* bl0 = (const float*)d_in[3];
  const float* Wr0 = (const float*)d_in[4];
  const float* Wl1 = (const float*)d_in[5];
  const float* bl1 = (const float*)d_in[6];
  const float* Wr1 = (const float*)d_in[7];
  const float* Wl2 = (const float*)d_in[8];
  const float* bl2 = (const float*)d_in[9];
  const float* Wr2 = (const float*)d_in[10];
  float* out = (float*)d_out;

  const int N = in_sizes[0] / 128;
  const int E = in_sizes[1] / 2;
  const int* src = ei;
  const int* dst = ei + E;

  char* w = (char*)d_ws;
  auto alloc = [&](size_t bytes) {
    char* p = w;
    w += (bytes + 255) & ~(size_t)255;
    return p;
  };
  int*    cnt     = (int*)alloc((size_t)N * 4);
  int*    row_ptr = (int*)alloc((size_t)(N + 1) * 4);
  int*    bflag   = (int*)alloc(32 * 4);
  ushort* rank    = (ushort*)alloc((size_t)E * 2 + 256);
  ushort* csr16   = (ushort*)alloc((size_t)E * 2 + 256);
  float*  inv     = (float*)alloc((size_t)N * 4);
  ushort* Whi0    = (ushort*)alloc((size_t)4 * 256 * 4 * 16);
  ushort* Whi1    = (ushort*)alloc((size_t)4 * 256 * 4 * 16);
  ushort* Whi2    = (ushort*)alloc((size_t)4 * 128 * 4 * 16);
  ushort* XB      = (ushort*)alloc((size_t)N * 128 * 2);  // x in bf16
  ushort* BZ      = (ushort*)alloc((size_t)N * 128 * 2);
  ushort* BRb     = (ushort*)alloc((size_t)N * 128 * 2);  // R in bf16
  ushort* B0      = (ushort*)alloc((size_t)N * 128 * 2);  // H in bf16
  (void)ws_size; (void)n_in; (void)out_size;

  const int ZB = ceil_div(N, 2048);             // zero-range blocks
  const int PS = ceil_div(N, SCAN_CHUNK);       // scan blocks (25 <= 32)
  const int PREP_B = 40 + ZB + ceil_div(N * 16, 256);

  // ---- prep: packs + cvt + zero (1 launch) ----
  k_prep<<<PREP_B, 256, 0, stream>>>(Wl0, Wr0, Whi0, Wl1, Wr1, Whi1,
                                     Wl2, Wr2, Whi2, x, XB, cnt, bflag, N, ZB);

  // ---- CSR build: count_rank -> lookback scan -> place (3 launches) ----
  k_count_rank<<<ceil_div(E, 1024), 256, 0, stream>>>(dst, cnt, rank, E);
  k_scan_lb<<<PS, SCAN_BS, 0, stream>>>(cnt, row_ptr, inv, bflag, N, PS);
  k_place<<<ceil_div(E, 1024), 256, 0, stream>>>(src, dst, rank, row_ptr, csr16, E);

  // ---- layer 0: xb -> (Zb,Rb) -> H1 bf16 (B0) ----
  k_gemm2b<128><<<ceil_div(N, 32), 256, 0, stream>>>(XB, Whi0, bl0, BZ, BRb, N);
  k_agg2<128, true, true><<<ceil_div(N, 4), 256, 0, stream>>>(BZ, BRb, row_ptr, csr16, inv, B0, N);

  // ---- layer 1: H1 bf16 -> (Zb,Rb) -> H2 bf16 (B0) ----
  k_gemm2b<128><<<ceil_div(N, 32), 256, 0, stream>>>(B0, Whi1, bl1, BZ, BRb, N);
  k_agg2<128, true, true><<<ceil_div(N, 4), 256, 0, stream>>>(BZ, BRb, row_ptr, csr16, inv, B0, N);

  // ---- layer 2: H2 bf16 -> (Zb,Rb) 64-wide -> out fp32 ----
  k_gemm2b<64><<<ceil_div(N, 32), 256, 0, stream>>>(B0, Whi2, bl2, BZ, BRb, N);
  k_agg2<64, false, false><<<ceil_div(N, 4), 256, 0, stream>>>(BZ, BRb, row_ptr, csr16, inv, out, N);
}